// Round 10
// baseline (152.865 us; speedup 1.0000x reference)
//
#include <hip/hip_runtime.h>
#include <math.h>

#define BB   16
#define CC   4
#define HH   640
#define WW   640
#define HWSZ (HH*WW)        // 409600 pixels per image
#define KM   16             // labels 1..16; 0 = background (derived)
#define NSUM (KM*CC)        // 64 channel-sum slots per image
#define NACC (NSUM+KM)      // + 16 counts = 80 slots per (image, block)
#define SIGMA_D 3.0f

#define GXB  64             // blocks per image -> 1024 blocks total (4/CU)
#define GPB  (HWSZ/4/GXB)   // 1600 int4-groups per block
#define NIT  (GPB/64)       // 25 wave-iterations, compile-time constant
#define NBLK (GXB*BB)       // 1024 total blocks
#define PART_FLOATS (BB*GXB*NACC)   // 81920 floats = 328 KB

// ---------------------------------------------------------------------------
// Single fused kernel: per-(image,label) register scan + threadfence-
// reduction finalize in the LAST block (kills the 2nd launch, ~10us).
// Locked-in lessons: runtime-indexed register arrays spill (r1/r2); LDS
// atomics ~224cyc/inst regardless of conflicts (r3/r4); barrier-gated tiles
// duty-cycle memory (r6); contended global atomics cost ~0.67us/K across
// XCDs (r5-r8) -> private per-block partials with plain stores (r9, 47us).
// Scan: label-split (wave w owns labels w*4+1..+4), 20 statically-indexed
// accumulators, barrier-free A/B register pipeline, exact 25-iter trip.
// grid = (GXB, B), block = 256.
// ---------------------------------------------------------------------------
__global__ __launch_bounds__(256) void seg_kernel(
    const float* __restrict__ pred, const int* __restrict__ labels,
    float* __restrict__ part, unsigned int* __restrict__ done_ctr,
    float* __restrict__ out)
{
    const int b     = blockIdx.y;
    const int t     = threadIdx.x;
    const int lane  = t & 63;
    const int w     = t >> 6;            // wave 0..3
    const int kbase = w * 4 + 1;         // this wave's labels

    const int4*   lab4 = (const int4*)(labels + (size_t)b * HWSZ);
    const float4* p0   = (const float4*)(pred + ((size_t)b * CC + 0) * HWSZ);
    const float4* p1   = (const float4*)(pred + ((size_t)b * CC + 1) * HWSZ);
    const float4* p2   = (const float4*)(pred + ((size_t)b * CC + 2) * HWSZ);
    const float4* p3   = (const float4*)(pred + ((size_t)b * CC + 3) * HWSZ);

    const int G0 = blockIdx.x * GPB + lane;   // this block's group window

    float acc[4][4];                     // [label][channel], static idx only
    float cnt[4];
    #pragma unroll
    for (int kk = 0; kk < 4; ++kk) {
        cnt[kk] = 0.f;
        #pragma unroll
        for (int c = 0; c < CC; ++c) acc[kk][c] = 0.f;
    }

#define PIXEL(LB, X0, X1, X2, X3)                                   \
    {                                                               \
        const int lbv = (LB);                                       \
        _Pragma("unroll")                                           \
        for (int kk = 0; kk < 4; ++kk) {                            \
            float m = (lbv == kbase + kk) ? 1.0f : 0.0f;            \
            acc[kk][0] = fmaf(m, (X0), acc[kk][0]);                 \
            acc[kk][1] = fmaf(m, (X1), acc[kk][1]);                 \
            acc[kk][2] = fmaf(m, (X2), acc[kk][2]);                 \
            acc[kk][3] = fmaf(m, (X3), acc[kk][3]);                 \
            cnt[kk]   += m;                                         \
        }                                                           \
    }

#define COMPUTE(L, Q0, Q1, Q2, Q3)                                  \
    PIXEL((L).x, (Q0).x, (Q1).x, (Q2).x, (Q3).x);                   \
    PIXEL((L).y, (Q0).y, (Q1).y, (Q2).y, (Q3).y);                   \
    PIXEL((L).z, (Q0).z, (Q1).z, (Q2).z, (Q3).z);                   \
    PIXEL((L).w, (Q0).w, (Q1).w, (Q2).w, (Q3).w);

    // software pipeline: named A/B register stages, 1-deep prefetch.
    int4   LA = lab4[G0];
    float4 A0 = p0[G0], A1 = p1[G0], A2 = p2[G0], A3 = p3[G0];
    int4   LBv;
    float4 B0, B1, B2, B3;

    #pragma unroll
    for (int it = 0; it < (NIT - 1) / 2; ++it) {       // 12 double-steps
        const int gB = G0 + (2 * it + 1) * 64;
        LBv = lab4[gB]; B0 = p0[gB]; B1 = p1[gB]; B2 = p2[gB]; B3 = p3[gB];
        COMPUTE(LA, A0, A1, A2, A3);
        const int gA = G0 + (2 * it + 2) * 64;
        LA = lab4[gA]; A0 = p0[gA]; A1 = p1[gA]; A2 = p2[gA]; A3 = p3[gA];
        COMPUTE(LBv, B0, B1, B2, B3);
    }
    COMPUTE(LA, A0, A1, A2, A3);                       // iteration 24

    // wave butterfly reduce (static indices); lane 0 stores 20 disjoint
    // slots into this block's PRIVATE partial slice (plain stores)
    #pragma unroll
    for (int kk = 0; kk < 4; ++kk) {
        #pragma unroll
        for (int c = 0; c < CC; ++c) {
            float v = acc[kk][c];
            v += __shfl_xor(v, 1);  v += __shfl_xor(v, 2);
            v += __shfl_xor(v, 4);  v += __shfl_xor(v, 8);
            v += __shfl_xor(v, 16); v += __shfl_xor(v, 32);
            acc[kk][c] = v;
        }
        float v = cnt[kk];
        v += __shfl_xor(v, 1);  v += __shfl_xor(v, 2);
        v += __shfl_xor(v, 4);  v += __shfl_xor(v, 8);
        v += __shfl_xor(v, 16); v += __shfl_xor(v, 32);
        cnt[kk] = v;
    }

    if (lane == 0) {
        float* pb = part + ((size_t)b * GXB + blockIdx.x) * NACC;
        #pragma unroll
        for (int kk = 0; kk < 4; ++kk) {
            const int kidx = kbase - 1 + kk;   // 0..15, disjoint across waves
            #pragma unroll
            for (int c = 0; c < CC; ++c)
                pb[kidx * 4 + c] = acc[kk][c];
            pb[NSUM + kidx] = cnt[kk];
        }
    }
#undef PIXEL
#undef COMPUTE

    // ---- threadfence reduction: last finished block runs the finalize ----
    __shared__ bool amLast;
    __threadfence();                      // device-scope release of partials
    __syncthreads();                      // all waves' stores issued
    if (t == 0) {
        unsigned int prev = atomicAdd(done_ctr, 1u);
        amLast = (prev == NBLK - 1);
    }
    __syncthreads();
    if (!amLast) return;
    __threadfence();                      // device-scope acquire

    __shared__ float red[BB * NACC];      // 1280 floats
    __shared__ float s_sumg[BB], s_P[BB], s_Kb[BB];
    const float F0 = logf(SIGMA_D * SIGMA_D + 1.0f);   // log(10)

    // stage 1: deterministic sum over the GXB per-block partials
    for (int s = t; s < BB * NACC; s += 256) {
        const int bi  = s / NACC;
        const int idx = s - bi * NACC;
        float v = 0.f;
        #pragma unroll 8
        for (int gx = 0; gx < GXB; ++gx)
            v += part[((size_t)bi * GXB + gx) * NACC + idx];
        red[s] = v;
    }
    __syncthreads();

    // stage 2: per-image math
    if (t < BB) {
        const float* wp = red + t * NACC;
        float cnt_sum = 0.f, sum_g = 0.f, Kb = 0.f;
        for (int k = 1; k <= KM; ++k) {
            float s0 = wp[(k-1)*4+0], s1 = wp[(k-1)*4+1];
            float s2 = wp[(k-1)*4+2], s3 = wp[(k-1)*4+3];
            float cn = wp[NSUM + (k-1)];
            float N  = sqrtf(s0*s0 + s1*s1 + s2*s2 + s3*s3);
            float r  = fmaxf(SIGMA_D - N, 0.f);
            float f  = logf(r*r + 1.0f);
            sum_g   += cn * f;
            cnt_sum += cn;
            if (cn > 0.f) Kb = (float)k;
        }
        float c0 = (float)HWSZ - cnt_sum;     // background count
        sum_g += c0 * F0;
        s_sumg[t] = sum_g;
        s_Kb[t]   = Kb;
        s_P[t]    = (Kb > 1.f) ? Kb * (Kb - 1.f) * 0.5f : 0.f;  // P_act
    }
    __syncthreads();

    // stage 3: cross-image combine
    if (t == 0) {
        double sumP = 0.0;
        for (int i = 0; i < BB; ++i) sumP += (double)s_P[i];
        double total = 0.0;
        for (int i = 0; i < BB; ++i) {
            double Kb   = (double)s_Kb[i];
            double Pact = (double)s_P[i];
            double own  = 0.0;
            if (Kb > 1.0)
                own = (Kb - 1.0) * (double)s_sumg[i]
                    + (double)HWSZ * (Pact - (Kb - 1.0)) * (double)F0;
            double other = (sumP - Pact) * (double)HWSZ * (double)F0;
            double scale = (Kb > 1.0) ? 1.0 / (Kb * (Kb - 1.0)) : Kb;
            total += scale * (own + other);
        }
        out[0] = (float)total;
    }
}

// ---------------------------------------------------------------------------
extern "C" void kernel_launch(void* const* d_in, const int* in_sizes, int n_in,
                              void* d_out, int out_size, void* d_ws, size_t ws_size,
                              hipStream_t stream)
{
    const float*  pred   = (const float*)d_in[0];
    const int*    labels = (const int*)d_in[1];
    float*        out    = (float*)d_out;
    float*        part   = (float*)d_ws;                       // 328 KB
    unsigned int* ctr    = (unsigned int*)((float*)d_ws + PART_FLOATS);

    // zero only the 4-byte done-counter (partials are fully overwritten)
    hipMemsetAsync(ctr, 0, sizeof(unsigned int), stream);

    dim3 grid(GXB, BB);
    seg_kernel<<<grid, 256, 0, stream>>>(pred, labels, part, ctr, out);
}

// Round 11
// 72.069 us; speedup vs baseline: 2.1211x; 2.1211x over previous
//
#include <hip/hip_runtime.h>
#include <math.h>

#define BB   16
#define CC   4
#define HH   640
#define WW   640
#define HWSZ (HH*WW)        // 409600 pixels per image
#define KM   16             // labels 1..16; 0 = background (derived)
#define NSUM (KM*CC)        // 64 channel-sum slots per image
#define NACC (NSUM+KM)      // + 16 counts = 80 slots per (image, block)
#define SIGMA_D 3.0f

#define GXB  160            // blocks per image -> 2560 blocks total
#define GPB  (HWSZ/4/GXB)   // 640 int4-groups per block
#define NIT  (GPB/64)       // 10 wave-iterations, compile-time constant

// ---------------------------------------------------------------------------
// Kernel 1: per-(image,label) channel sums + counts.
// HYBRID 2x2 SPLIT register scan: wave w owns 8 labels ((w>>1)*8+1..+8) x
// 2 channels ((w&1)*2..+1). vs r7 label-split: same VALU (8cmp+16fma+8add
// vs 4cmp+16fma+4add per px) but lane-delivered bytes 524->314 MB and
// loads/iter 5->3. vs r8 channel-split: 2.5x less VALU. Atomic-free private
// per-block partial stores (r9: contended global atomics cost ~0.67us/K,
// r8's 256K atomics = 170us). Locked-in lessons: runtime-indexed register
// arrays spill (r1/r2); LDS atomics ~224cyc/inst (r3/r4); barrier-gated
// tiles duty-cycle memory (r6); kernel fusion via threadfence wrecks the
// scan codegen (r10) -> two kernels.
// grid = (GXB, B), block = 256, 10 iters/wave exactly (4 pairs + tail pair).
// ---------------------------------------------------------------------------
__global__ __launch_bounds__(256) void seg_kernel(
    const float* __restrict__ pred, const int* __restrict__ labels,
    float* __restrict__ part)
{
    const int b     = blockIdx.y;
    const int t     = threadIdx.x;
    const int lane  = t & 63;
    const int w     = t >> 6;            // wave 0..3
    const int kb    = (w >> 1) * 8 + 1;  // first label of this wave's 8
    const int c0    = (w & 1) * 2;       // first of this wave's 2 channels

    const int4*   lab4 = (const int4*)(labels + (size_t)b * HWSZ);
    const float4* pc0  = (const float4*)(pred + ((size_t)b * CC + c0) * HWSZ);
    const float4* pc1  = (const float4*)(pred + ((size_t)b * CC + c0 + 1) * HWSZ);

    const int G0 = blockIdx.x * GPB + lane;   // this block's group window

    float acc[8][2];                     // [label][channel], static idx only
    float cnt[8];                        // counted by all, stored by even waves
    #pragma unroll
    for (int kk = 0; kk < 8; ++kk) {
        cnt[kk] = 0.f;
        acc[kk][0] = 0.f;
        acc[kk][1] = 0.f;
    }

#define PIXEL(LB, X0, X1)                                           \
    {                                                               \
        const int lbv = (LB);                                       \
        _Pragma("unroll")                                           \
        for (int kk = 0; kk < 8; ++kk) {                            \
            float m = (lbv == kb + kk) ? 1.0f : 0.0f;               \
            acc[kk][0] = fmaf(m, (X0), acc[kk][0]);                 \
            acc[kk][1] = fmaf(m, (X1), acc[kk][1]);                 \
            cnt[kk]   += m;                                         \
        }                                                           \
    }

#define COMPUTE(L, Q0, Q1)                                          \
    PIXEL((L).x, (Q0).x, (Q1).x);                                   \
    PIXEL((L).y, (Q0).y, (Q1).y);                                   \
    PIXEL((L).z, (Q0).z, (Q1).z);                                   \
    PIXEL((L).w, (Q0).w, (Q1).w);

    // software pipeline: named A/B register stages, 1-deep prefetch
    // (3 loads in flight during each COMPUTE).
    int4   LA = lab4[G0];
    float4 A0 = pc0[G0], A1 = pc1[G0];
    int4   LBv;
    float4 B0, B1;

    #pragma unroll
    for (int it = 0; it < (NIT - 2) / 2; ++it) {       // 4 pairs: g0..g7
        const int gB = G0 + (2 * it + 1) * 64;
        LBv = lab4[gB]; B0 = pc0[gB]; B1 = pc1[gB];
        COMPUTE(LA, A0, A1);
        const int gA = G0 + (2 * it + 2) * 64;
        LA = lab4[gA]; A0 = pc0[gA]; A1 = pc1[gA];
        COMPUTE(LBv, B0, B1);
    }
    {                                                  // tail: g8, g9
        const int gB = G0 + (NIT - 1) * 64;
        LBv = lab4[gB]; B0 = pc0[gB]; B1 = pc1[gB];
        COMPUTE(LA, A0, A1);
        COMPUTE(LBv, B0, B1);
    }

    // wave butterfly reduce (static indices); lane 0 stores disjoint slots
    // into this block's PRIVATE partial slice (plain stores, no atomics)
    #pragma unroll
    for (int kk = 0; kk < 8; ++kk) {
        #pragma unroll
        for (int c = 0; c < 2; ++c) {
            float v = acc[kk][c];
            v += __shfl_xor(v, 1);  v += __shfl_xor(v, 2);
            v += __shfl_xor(v, 4);  v += __shfl_xor(v, 8);
            v += __shfl_xor(v, 16); v += __shfl_xor(v, 32);
            acc[kk][c] = v;
        }
        float v = cnt[kk];
        v += __shfl_xor(v, 1);  v += __shfl_xor(v, 2);
        v += __shfl_xor(v, 4);  v += __shfl_xor(v, 8);
        v += __shfl_xor(v, 16); v += __shfl_xor(v, 32);
        cnt[kk] = v;
    }

    if (lane == 0) {
        float* pb = part + ((size_t)b * GXB + blockIdx.x) * NACC;
        #pragma unroll
        for (int kk = 0; kk < 8; ++kk) {
            const int kidx = kb - 1 + kk;          // 0..15
            pb[kidx * 4 + c0]     = acc[kk][0];
            pb[kidx * 4 + c0 + 1] = acc[kk][1];
            if ((w & 1) == 0)                      // wave-uniform branch
                pb[NSUM + kidx] = cnt[kk];
        }
    }
#undef PIXEL
#undef COMPUTE
}

// ---------------------------------------------------------------------------
// Kernel 2: reduce GXB partials per (image, slot), then the scalar epilogue.
// ---------------------------------------------------------------------------
__global__ __launch_bounds__(256) void finalize_kernel(
    const float* __restrict__ part, float* __restrict__ out)
{
    __shared__ float red[BB * NACC];          // 1280 floats
    __shared__ float s_sumg[BB], s_P[BB], s_Kb[BB];
    const float F0 = logf(SIGMA_D * SIGMA_D + 1.0f);   // log(10)
    const int t = threadIdx.x;

    // stage 1: deterministic sum over the GXB per-block partials
    for (int s = t; s < BB * NACC; s += 256) {
        const int bi  = s / NACC;
        const int idx = s - bi * NACC;
        float v = 0.f;
        #pragma unroll 8
        for (int gx = 0; gx < GXB; ++gx)
            v += part[((size_t)bi * GXB + gx) * NACC + idx];
        red[s] = v;
    }
    __syncthreads();

    // stage 2: per-image math
    if (t < BB) {
        const float* wp = red + t * NACC;
        float cnt_sum = 0.f, sum_g = 0.f, Kb = 0.f;
        for (int k = 1; k <= KM; ++k) {
            float s0 = wp[(k-1)*4+0], s1 = wp[(k-1)*4+1];
            float s2 = wp[(k-1)*4+2], s3 = wp[(k-1)*4+3];
            float cn = wp[NSUM + (k-1)];
            float N  = sqrtf(s0*s0 + s1*s1 + s2*s2 + s3*s3);
            float r  = fmaxf(SIGMA_D - N, 0.f);
            float f  = logf(r*r + 1.0f);
            sum_g   += cn * f;
            cnt_sum += cn;
            if (cn > 0.f) Kb = (float)k;
        }
        float c0 = (float)HWSZ - cnt_sum;     // background count
        sum_g += c0 * F0;
        s_sumg[t] = sum_g;
        s_Kb[t]   = Kb;
        s_P[t]    = (Kb > 1.f) ? Kb * (Kb - 1.f) * 0.5f : 0.f;  // P_act
    }
    __syncthreads();

    // stage 3: cross-image combine
    if (t == 0) {
        double sumP = 0.0;
        for (int i = 0; i < BB; ++i) sumP += (double)s_P[i];
        double total = 0.0;
        for (int i = 0; i < BB; ++i) {
            double Kb   = (double)s_Kb[i];
            double Pact = (double)s_P[i];
            double own  = 0.0;
            if (Kb > 1.0)
                own = (Kb - 1.0) * (double)s_sumg[i]
                    + (double)HWSZ * (Pact - (Kb - 1.0)) * (double)F0;
            double other = (sumP - Pact) * (double)HWSZ * (double)F0;
            double scale = (Kb > 1.0) ? 1.0 / (Kb * (Kb - 1.0)) : Kb;
            total += scale * (own + other);
        }
        out[0] = (float)total;
    }
}

// ---------------------------------------------------------------------------
extern "C" void kernel_launch(void* const* d_in, const int* in_sizes, int n_in,
                              void* d_out, int out_size, void* d_ws, size_t ws_size,
                              hipStream_t stream)
{
    const float* pred   = (const float*)d_in[0];
    const int*   labels = (const int*)d_in[1];
    float*       out    = (float*)d_out;
    float*       part   = (float*)d_ws;       // 16*160*80*4 B = 819 KB scratch

    dim3 grid(GXB, BB);
    seg_kernel<<<grid, 256, 0, stream>>>(pred, labels, part);
    finalize_kernel<<<1, 256, 0, stream>>>(part, out);
}

// Round 12
// 66.434 us; speedup vs baseline: 2.3010x; 1.0848x over previous
//
#include <hip/hip_runtime.h>
#include <math.h>

#define BB   16
#define CC   4
#define HH   640
#define WW   640
#define HWSZ (HH*WW)        // 409600 pixels per image
#define KM   16             // labels 1..16; 0 = background (derived)
#define NSUM (KM*CC)        // 64 channel-sum slots per image
#define NACC (NSUM+KM)      // + 16 counts = 80 slots per image
#define SIGMA_D 3.0f

#define GXB   80            // blocks per image -> 1280 blocks total
#define GPB   (HWSZ/4/GXB)  // 1280 int4-groups per block
#define HALFG (GPB/2)       // 640 groups per wave-pair
#define NIT   (HALFG/64)    // 10 wave-iterations, compile-time constant
#define NSLICE (GXB*2)      // 160 partial slices per image (block x pair)
#define ROWS  (BB*NACC)     // 1280 partial rows
#define PART_FLOATS (ROWS*NSLICE)   // 204800 floats = 819 KB

// ---------------------------------------------------------------------------
// Kernel 1: per-(image,label) channel sums + counts.
// 2x2 LABEL x PIXEL SPLIT register scan: wave pair p = w>>1 owns pixel-half
// p of the block window; within a pair, wave owns 8 labels x ALL 4 channels
// (32 static accumulators). Each pixel is visited by 2 waves (not 4): lane-
// delivered bytes 524 -> 262 MB. r9's scan measured ~62 B/cyc/CU = the L1
// delivery ceiling -> halving bytes should halve scan time. Counts via
// __ballot+popcll (SALU-side, wave-uniform, no butterfly; r2 proved the
// codegen, its failure was acc spills). Partials stored TRANSPOSED
// (part[row*NSLICE+slice]) so the 1-block finalize reads each row as 40
// contiguous float4 (r11 lesson: strided GXB-way finalize reduction is
// latency-bound and scales badly).
// Locked-in: runtime-indexed register arrays spill (r1/r2); LDS atomics
// ~224cyc/inst (r3/r4); barrier-gated tiles duty-cycle memory (r6);
// contended global atomics ~0.67us/K (r5-r8); threadfence fusion wrecks
// codegen (r10).  grid = (GXB, B), block = 256.
// ---------------------------------------------------------------------------
__global__ __launch_bounds__(256) void seg_kernel(
    const float* __restrict__ pred, const int* __restrict__ labels,
    float* __restrict__ part)
{
    const int b     = blockIdx.y;
    const int t     = threadIdx.x;
    const int lane  = t & 63;
    const int w     = t >> 6;            // wave 0..3
    const int pair  = w >> 1;            // pixel half
    const int lhalf = w & 1;             // label half
    const int kb    = lhalf * 8 + 1;     // first of this wave's 8 labels

    const int4*   lab4 = (const int4*)(labels + (size_t)b * HWSZ);
    const float4* p0   = (const float4*)(pred + ((size_t)b * CC + 0) * HWSZ);
    const float4* p1   = (const float4*)(pred + ((size_t)b * CC + 1) * HWSZ);
    const float4* p2   = (const float4*)(pred + ((size_t)b * CC + 2) * HWSZ);
    const float4* p3   = (const float4*)(pred + ((size_t)b * CC + 3) * HWSZ);

    const int G0 = blockIdx.x * GPB + pair * HALFG + lane;

    float acc[8][4];                     // [label][channel], static idx only
    int   cnt[8];                        // wave-uniform ballot counts
    #pragma unroll
    for (int kk = 0; kk < 8; ++kk) {
        cnt[kk] = 0;
        #pragma unroll
        for (int c = 0; c < CC; ++c) acc[kk][c] = 0.f;
    }

#define PIXEL(LB, X0, X1, X2, X3)                                   \
    {                                                               \
        const int lbv = (LB);                                       \
        _Pragma("unroll")                                           \
        for (int kk = 0; kk < 8; ++kk) {                            \
            const bool hit = (lbv == kb + kk);                      \
            cnt[kk] += (int)__popcll(__ballot(hit));                \
            const float m = hit ? 1.0f : 0.0f;                      \
            acc[kk][0] = fmaf(m, (X0), acc[kk][0]);                 \
            acc[kk][1] = fmaf(m, (X1), acc[kk][1]);                 \
            acc[kk][2] = fmaf(m, (X2), acc[kk][2]);                 \
            acc[kk][3] = fmaf(m, (X3), acc[kk][3]);                 \
        }                                                           \
    }

#define COMPUTE(L, Q0, Q1, Q2, Q3)                                  \
    PIXEL((L).x, (Q0).x, (Q1).x, (Q2).x, (Q3).x);                   \
    PIXEL((L).y, (Q0).y, (Q1).y, (Q2).y, (Q3).y);                   \
    PIXEL((L).z, (Q0).z, (Q1).z, (Q2).z, (Q3).z);                   \
    PIXEL((L).w, (Q0).w, (Q1).w, (Q2).w, (Q3).w);

    // software pipeline: named A/B register stages, 1-deep prefetch.
    int4   LA = lab4[G0];
    float4 A0 = p0[G0], A1 = p1[G0], A2 = p2[G0], A3 = p3[G0];
    int4   LBv;
    float4 B0, B1, B2, B3;

    #pragma unroll
    for (int it = 0; it < (NIT - 2) / 2; ++it) {       // 4 pairs: g0..g7
        const int gB = G0 + (2 * it + 1) * 64;
        LBv = lab4[gB]; B0 = p0[gB]; B1 = p1[gB]; B2 = p2[gB]; B3 = p3[gB];
        COMPUTE(LA, A0, A1, A2, A3);
        const int gA = G0 + (2 * it + 2) * 64;
        LA = lab4[gA]; A0 = p0[gA]; A1 = p1[gA]; A2 = p2[gA]; A3 = p3[gA];
        COMPUTE(LBv, B0, B1, B2, B3);
    }
    {                                                  // tail: g8, g9
        const int gB = G0 + (NIT - 1) * 64;
        LBv = lab4[gB]; B0 = p0[gB]; B1 = p1[gB]; B2 = p2[gB]; B3 = p3[gB];
        COMPUTE(LA, A0, A1, A2, A3);
        COMPUTE(LBv, B0, B1, B2, B3);
    }
#undef PIXEL
#undef COMPUTE

    // butterfly-reduce the 32 channel sums (counts are already wave-uniform)
    #pragma unroll
    for (int kk = 0; kk < 8; ++kk) {
        #pragma unroll
        for (int c = 0; c < CC; ++c) {
            float v = acc[kk][c];
            v += __shfl_xor(v, 1);  v += __shfl_xor(v, 2);
            v += __shfl_xor(v, 4);  v += __shfl_xor(v, 8);
            v += __shfl_xor(v, 16); v += __shfl_xor(v, 32);
            acc[kk][c] = v;
        }
    }

    // lane 0: 40 disjoint plain stores, transposed layout part[row][slice]
    if (lane == 0) {
        const int slice = blockIdx.x * 2 + pair;       // 0..NSLICE-1
        const size_t rb = (size_t)b * NACC;
        #pragma unroll
        for (int kk = 0; kk < 8; ++kk) {
            const int kidx = kb - 1 + kk;              // 0..15
            #pragma unroll
            for (int c = 0; c < CC; ++c)
                part[(rb + kidx * 4 + c) * NSLICE + slice] = acc[kk][c];
            part[(rb + NSUM + kidx) * NSLICE + slice] = (float)cnt[kk];
        }
    }
}

// ---------------------------------------------------------------------------
// Kernel 2: reduce NSLICE partials per row (contiguous float4), then epilogue.
// ---------------------------------------------------------------------------
__global__ __launch_bounds__(256) void finalize_kernel(
    const float* __restrict__ part, float* __restrict__ out)
{
    __shared__ float red[ROWS];               // 1280 floats
    __shared__ float s_sumg[BB], s_P[BB], s_Kb[BB];
    const float F0 = logf(SIGMA_D * SIGMA_D + 1.0f);   // log(10)
    const int t = threadIdx.x;

    // stage 1: each thread sums whole rows (160 consecutive floats = 40 f4)
    for (int r = t; r < ROWS; r += 256) {
        const float4* pr = (const float4*)(part + (size_t)r * NSLICE);
        float4 v4 = make_float4(0.f, 0.f, 0.f, 0.f);
        #pragma unroll 8
        for (int j = 0; j < NSLICE / 4; ++j) {
            float4 x = pr[j];
            v4.x += x.x; v4.y += x.y; v4.z += x.z; v4.w += x.w;
        }
        red[r] = v4.x + v4.y + v4.z + v4.w;
    }
    __syncthreads();

    // stage 2: per-image math
    if (t < BB) {
        const float* wp = red + t * NACC;
        float cnt_sum = 0.f, sum_g = 0.f, Kb = 0.f;
        for (int k = 1; k <= KM; ++k) {
            float s0 = wp[(k-1)*4+0], s1 = wp[(k-1)*4+1];
            float s2 = wp[(k-1)*4+2], s3 = wp[(k-1)*4+3];
            float cn = wp[NSUM + (k-1)];
            float N  = sqrtf(s0*s0 + s1*s1 + s2*s2 + s3*s3);
            float r  = fmaxf(SIGMA_D - N, 0.f);
            float f  = logf(r*r + 1.0f);
            sum_g   += cn * f;
            cnt_sum += cn;
            if (cn > 0.f) Kb = (float)k;
        }
        float c0 = (float)HWSZ - cnt_sum;     // background count
        sum_g += c0 * F0;
        s_sumg[t] = sum_g;
        s_Kb[t]   = Kb;
        s_P[t]    = (Kb > 1.f) ? Kb * (Kb - 1.f) * 0.5f : 0.f;  // P_act
    }
    __syncthreads();

    // stage 3: cross-image combine
    if (t == 0) {
        double sumP = 0.0;
        for (int i = 0; i < BB; ++i) sumP += (double)s_P[i];
        double total = 0.0;
        for (int i = 0; i < BB; ++i) {
            double Kb   = (double)s_Kb[i];
            double Pact = (double)s_P[i];
            double own  = 0.0;
            if (Kb > 1.0)
                own = (Kb - 1.0) * (double)s_sumg[i]
                    + (double)HWSZ * (Pact - (Kb - 1.0)) * (double)F0;
            double other = (sumP - Pact) * (double)HWSZ * (double)F0;
            double scale = (Kb > 1.0) ? 1.0 / (Kb * (Kb - 1.0)) : Kb;
            total += scale * (own + other);
        }
        out[0] = (float)total;
    }
}

// ---------------------------------------------------------------------------
extern "C" void kernel_launch(void* const* d_in, const int* in_sizes, int n_in,
                              void* d_out, int out_size, void* d_ws, size_t ws_size,
                              hipStream_t stream)
{
    const float* pred   = (const float*)d_in[0];
    const int*   labels = (const int*)d_in[1];
    float*       out    = (float*)d_out;
    float*       part   = (float*)d_ws;       // 819 KB scratch, fully overwritten

    dim3 grid(GXB, BB);
    seg_kernel<<<grid, 256, 0, stream>>>(pred, labels, part);
    finalize_kernel<<<1, 256, 0, stream>>>(part, out);
}

// Round 13
// 47.932 us; speedup vs baseline: 3.1892x; 1.3860x over previous
//
#include <hip/hip_runtime.h>
#include <math.h>

#define BB   16
#define CC   4
#define HH   640
#define WW   640
#define HWSZ (HH*WW)        // 409600 pixels per image
#define KM   16             // labels 1..16; 0 = background (derived)
#define NSUM (KM*CC)        // 64 channel-sum slots per image
#define NACC (NSUM+KM)      // + 16 counts = 80 slots per image
#define SIGMA_D 3.0f

#define GXB   100           // blocks per image -> 1600 blocks total
#define GPB   (HWSZ/4/GXB)  // 1024 int4-groups per block
#define NIT   (GPB/64)      // 16 wave-iterations, compile-time constant
#define NSLICE GXB          // one partial slice per block
#define ROWS  (BB*NACC)     // 1280 partial rows
#define PART_FLOATS (ROWS*NSLICE)   // 128000 floats = 512 KB

// ---------------------------------------------------------------------------
// Kernel 1: per-(image,label) channel sums + counts.
// r9's label-split register scan with a 2-DEEP X/Y/Z software pipeline.
// Evidence r7/r8/r9: both 4x-redundant-read and 1x-read scans intercept at
// ~28-33us with VALUBusy ~24% -> latency-bound (L3 hit ~700-1000cyc exposed
// per iter at 1-deep / 5-loads-in-flight), not delivery- or issue-bound.
// Fix: 10 loads in flight (2 groups ahead), GXB=100 for more resident
// blocks. NO ballots (r12: +50% issue slots -> 63us). Counts as float fma.
// Partials stored TRANSPOSED part[row*NSLICE+slice]; f4-row finalize ~1us
// (r12 validated). Locked-in: runtime-indexed register arrays spill (r1/r2);
// LDS atomics ~224cyc/inst (r3/r4); barrier lockstep duty-cycles memory
// (r6); contended global atomics ~0.67us/K (r5-r8); threadfence fusion
// wrecks codegen (r10).  grid = (GXB, B), block = 256.
// ---------------------------------------------------------------------------
__global__ __launch_bounds__(256) void seg_kernel(
    const float* __restrict__ pred, const int* __restrict__ labels,
    float* __restrict__ part)
{
    const int b     = blockIdx.y;
    const int t     = threadIdx.x;
    const int lane  = t & 63;
    const int w     = t >> 6;            // wave 0..3
    const int kbase = w * 4 + 1;         // this wave's labels

    const int4*   lab4 = (const int4*)(labels + (size_t)b * HWSZ);
    const float4* p0   = (const float4*)(pred + ((size_t)b * CC + 0) * HWSZ);
    const float4* p1   = (const float4*)(pred + ((size_t)b * CC + 1) * HWSZ);
    const float4* p2   = (const float4*)(pred + ((size_t)b * CC + 2) * HWSZ);
    const float4* p3   = (const float4*)(pred + ((size_t)b * CC + 3) * HWSZ);

    const int G0 = blockIdx.x * GPB + lane;   // this block's group window

    float acc[4][4];                     // [label][channel], static idx only
    float cnt[4];
    #pragma unroll
    for (int kk = 0; kk < 4; ++kk) {
        cnt[kk] = 0.f;
        #pragma unroll
        for (int c = 0; c < CC; ++c) acc[kk][c] = 0.f;
    }

#define PIXEL(LB, X0, X1, X2, X3)                                   \
    {                                                               \
        const int lbv = (LB);                                       \
        _Pragma("unroll")                                           \
        for (int kk = 0; kk < 4; ++kk) {                            \
            float m = (lbv == kbase + kk) ? 1.0f : 0.0f;            \
            acc[kk][0] = fmaf(m, (X0), acc[kk][0]);                 \
            acc[kk][1] = fmaf(m, (X1), acc[kk][1]);                 \
            acc[kk][2] = fmaf(m, (X2), acc[kk][2]);                 \
            acc[kk][3] = fmaf(m, (X3), acc[kk][3]);                 \
            cnt[kk]   += m;                                         \
        }                                                           \
    }

#define COMPUTE(L, Q0, Q1, Q2, Q3)                                  \
    PIXEL((L).x, (Q0).x, (Q1).x, (Q2).x, (Q3).x);                   \
    PIXEL((L).y, (Q0).y, (Q1).y, (Q2).y, (Q3).y);                   \
    PIXEL((L).z, (Q0).z, (Q1).z, (Q2).z, (Q3).z);                   \
    PIXEL((L).w, (Q0).w, (Q1).w, (Q2).w, (Q3).w);

#define LD(ST, GI)                                                  \
    { const int g_ = G0 + (GI) * 64;                                \
      L##ST = lab4[g_];                                             \
      ST##0 = p0[g_]; ST##1 = p1[g_]; ST##2 = p2[g_]; ST##3 = p3[g_]; }

    // 2-deep pipeline: stages X, Y, Z; at each step i, load g=i+2 (clamped)
    // into stage (i+2)%3 and compute stage i%3. 10 loads in flight.
    int4   LX, LY, LZ;
    float4 X0, X1, X2, X3, Y0, Y1, Y2, Y3, Z0, Z1, Z2, Z3;

    LD(X, 0);
    LD(Y, 1);
    #pragma unroll
    for (int m = 0; m < NIT / 3; ++m) {            // 5 macro-steps: i=3m..3m+2
        const int i = 3 * m;
        const int l0 = (i + 2 < NIT) ? i + 2 : NIT - 1;
        const int l1 = (i + 3 < NIT) ? i + 3 : NIT - 1;
        const int l2 = (i + 4 < NIT) ? i + 4 : NIT - 1;
        LD(Z, l0); COMPUTE(LX, X0, X1, X2, X3);
        LD(X, l1); COMPUTE(LY, Y0, Y1, Y2, Y3);
        LD(Y, l2); COMPUTE(LZ, Z0, Z1, Z2, Z3);
    }
    COMPUTE(LX, X0, X1, X2, X3);                   // final step i = 15 (g15)
#undef PIXEL
#undef COMPUTE
#undef LD

    // wave butterfly reduce (static indices); lane 0 stores 20 disjoint
    // slots, transposed layout part[row*NSLICE + blockIdx.x]
    #pragma unroll
    for (int kk = 0; kk < 4; ++kk) {
        #pragma unroll
        for (int c = 0; c < CC; ++c) {
            float v = acc[kk][c];
            v += __shfl_xor(v, 1);  v += __shfl_xor(v, 2);
            v += __shfl_xor(v, 4);  v += __shfl_xor(v, 8);
            v += __shfl_xor(v, 16); v += __shfl_xor(v, 32);
            acc[kk][c] = v;
        }
        float v = cnt[kk];
        v += __shfl_xor(v, 1);  v += __shfl_xor(v, 2);
        v += __shfl_xor(v, 4);  v += __shfl_xor(v, 8);
        v += __shfl_xor(v, 16); v += __shfl_xor(v, 32);
        cnt[kk] = v;
    }

    if (lane == 0) {
        const size_t rb = (size_t)b * NACC;
        #pragma unroll
        for (int kk = 0; kk < 4; ++kk) {
            const int kidx = kbase - 1 + kk;       // 0..15, disjoint per wave
            #pragma unroll
            for (int c = 0; c < CC; ++c)
                part[(rb + kidx * 4 + c) * NSLICE + blockIdx.x] = acc[kk][c];
            part[(rb + NSUM + kidx) * NSLICE + blockIdx.x] = cnt[kk];
        }
    }
}

// ---------------------------------------------------------------------------
// Kernel 2: reduce NSLICE partials per row (contiguous float4), then epilogue.
// ---------------------------------------------------------------------------
__global__ __launch_bounds__(256) void finalize_kernel(
    const float* __restrict__ part, float* __restrict__ out)
{
    __shared__ float red[ROWS];               // 1280 floats
    __shared__ float s_sumg[BB], s_P[BB], s_Kb[BB];
    const float F0 = logf(SIGMA_D * SIGMA_D + 1.0f);   // log(10)
    const int t = threadIdx.x;

    // stage 1: each thread sums whole rows (100 consecutive floats = 25 f4)
    for (int r = t; r < ROWS; r += 256) {
        const float4* pr = (const float4*)(part + (size_t)r * NSLICE);
        float4 v4 = make_float4(0.f, 0.f, 0.f, 0.f);
        #pragma unroll 5
        for (int j = 0; j < NSLICE / 4; ++j) {
            float4 x = pr[j];
            v4.x += x.x; v4.y += x.y; v4.z += x.z; v4.w += x.w;
        }
        red[r] = v4.x + v4.y + v4.z + v4.w;
    }
    __syncthreads();

    // stage 2: per-image math
    if (t < BB) {
        const float* wp = red + t * NACC;
        float cnt_sum = 0.f, sum_g = 0.f, Kb = 0.f;
        for (int k = 1; k <= KM; ++k) {
            float s0 = wp[(k-1)*4+0], s1 = wp[(k-1)*4+1];
            float s2 = wp[(k-1)*4+2], s3 = wp[(k-1)*4+3];
            float cn = wp[NSUM + (k-1)];
            float N  = sqrtf(s0*s0 + s1*s1 + s2*s2 + s3*s3);
            float r  = fmaxf(SIGMA_D - N, 0.f);
            float f  = logf(r*r + 1.0f);
            sum_g   += cn * f;
            cnt_sum += cn;
            if (cn > 0.f) Kb = (float)k;
        }
        float c0 = (float)HWSZ - cnt_sum;     // background count
        sum_g += c0 * F0;
        s_sumg[t] = sum_g;
        s_Kb[t]   = Kb;
        s_P[t]    = (Kb > 1.f) ? Kb * (Kb - 1.f) * 0.5f : 0.f;  // P_act
    }
    __syncthreads();

    // stage 3: cross-image combine
    if (t == 0) {
        double sumP = 0.0;
        for (int i = 0; i < BB; ++i) sumP += (double)s_P[i];
        double total = 0.0;
        for (int i = 0; i < BB; ++i) {
            double Kb   = (double)s_Kb[i];
            double Pact = (double)s_P[i];
            double own  = 0.0;
            if (Kb > 1.0)
                own = (Kb - 1.0) * (double)s_sumg[i]
                    + (double)HWSZ * (Pact - (Kb - 1.0)) * (double)F0;
            double other = (sumP - Pact) * (double)HWSZ * (double)F0;
            double scale = (Kb > 1.0) ? 1.0 / (Kb * (Kb - 1.0)) : Kb;
            total += scale * (own + other);
        }
        out[0] = (float)total;
    }
}

// ---------------------------------------------------------------------------
extern "C" void kernel_launch(void* const* d_in, const int* in_sizes, int n_in,
                              void* d_out, int out_size, void* d_ws, size_t ws_size,
                              hipStream_t stream)
{
    const float* pred   = (const float*)d_in[0];
    const int*   labels = (const int*)d_in[1];
    float*       out    = (float*)d_out;
    float*       part   = (float*)d_ws;       // 512 KB scratch, fully overwritten

    dim3 grid(GXB, BB);
    seg_kernel<<<grid, 256, 0, stream>>>(pred, labels, part);
    finalize_kernel<<<1, 256, 0, stream>>>(part, out);
}